// Round 2
// baseline (1170.249 us; speedup 1.0000x reference)
//
#include <hip/hip_runtime.h>
#include <math.h>

#define B       32
#define S_FULL  512
#define S       511            // sliced length (drop token 0)
#define D       768
#define NROWS   (B * S)        // 16352

#define TM 128
#define TN 128                 // j-chunk width
#define TK 16
#define ASTR 132               // padded LDS row stride (floats), keeps 16B align
#define NCHUNK 4
#define NITILE 4
#define NKT (D / TK)           // 48

// ---------------- 1. row inverse norms (wave per row) ----------------
__global__ __launch_bounds__(256) void norm_kernel(
    const float* __restrict__ text, const float* __restrict__ target,
    float* __restrict__ inv_t, float* __restrict__ inv_g)
{
    int row = blockIdx.x * 4 + (threadIdx.x >> 6);
    if (row >= NROWS) return;
    int lane = threadIdx.x & 63;
    int b = row / S, i = row - b * S;
    const float4* pt = (const float4*)(text   + (size_t)(b * S_FULL + i + 1) * D);
    const float4* pg = (const float4*)(target + (size_t)(b * S_FULL + i + 1) * D);
    float st = 0.f, sg = 0.f;
    #pragma unroll
    for (int q = 0; q < 3; ++q) {
        float4 a = pt[lane + 64 * q];
        float4 g = pg[lane + 64 * q];
        st += a.x * a.x + a.y * a.y + a.z * a.z + a.w * a.w;
        sg += g.x * g.x + g.y * g.y + g.z * g.z + g.w * g.w;
    }
    #pragma unroll
    for (int m = 32; m > 0; m >>= 1) {
        st += __shfl_xor(st, m, 64);
        sg += __shfl_xor(sg, m, 64);
    }
    if (lane == 0) {
        inv_t[row] = (st > 0.f) ? 1.0f / sqrtf(st) : 0.f;
        inv_g[row] = (sg > 0.f) ? 1.0f / sqrtf(sg) : 0.f;
    }
}

// ---------------- 2. fp32 GEMM + per-chunk argmax ----------------
// grid (NCHUNK, NITILE, B); block 256; tile 128x128, micro 8x8/thread
__global__ __launch_bounds__(256, 2) void simargmax_kernel(
    const float* __restrict__ text, const float* __restrict__ target,
    const float* __restrict__ inv_t, const float* __restrict__ inv_g,
    float* __restrict__ pv, int* __restrict__ pi)
{
    __shared__ float As[2][TK * ASTR];
    __shared__ float Bs[2][TK * ASTR];

    const int jc = blockIdx.x;
    const int j0 = jc * TN;
    const int i0 = blockIdx.y * TM;
    const int b  = blockIdx.z;
    const int t  = threadIdx.x;
    const int tx = t & 15, ty = t >> 4;

    const float* Abase = text   + (size_t)b * S_FULL * D + D;   // skip token 0
    const float* Bbase = target + (size_t)b * S_FULL * D + D;
    const float* invT = inv_t + b * S;
    const float* invG = inv_g + b * S;

    // staging map: thread t handles rows r0, r0+64 at k-quad kq
    const int r0 = t >> 2;          // 0..63
    const int kq = (t & 3) * 4;     // 0,4,8,12

    float4 pa[2], pb[2];
    float  sa[2], sb[2];

    auto stage_load = [&](int k0) {
        #pragma unroll
        for (int h = 0; h < 2; ++h) {
            int row = r0 + h * 64;
            int gi = i0 + row;
            if (gi < S) {
                pa[h] = *(const float4*)(Abase + (size_t)gi * D + k0 + kq);
                sa[h] = invT[gi];
            } else { pa[h] = make_float4(0.f,0.f,0.f,0.f); sa[h] = 0.f; }
            int gj = j0 + row;
            if (gj < S) {
                pb[h] = *(const float4*)(Bbase + (size_t)gj * D + k0 + kq);
                sb[h] = invG[gj];
            } else { pb[h] = make_float4(0.f,0.f,0.f,0.f); sb[h] = 0.f; }
        }
    };
    auto stage_store = [&](int buf) {
        #pragma unroll
        for (int h = 0; h < 2; ++h) {
            int row = r0 + h * 64;
            float* a = &As[buf][0];
            a[(kq + 0) * ASTR + row] = pa[h].x * sa[h];
            a[(kq + 1) * ASTR + row] = pa[h].y * sa[h];
            a[(kq + 2) * ASTR + row] = pa[h].z * sa[h];
            a[(kq + 3) * ASTR + row] = pa[h].w * sa[h];
            float* bb = &Bs[buf][0];
            bb[(kq + 0) * ASTR + row] = pb[h].x * sb[h];
            bb[(kq + 1) * ASTR + row] = pb[h].y * sb[h];
            bb[(kq + 2) * ASTR + row] = pb[h].z * sb[h];
            bb[(kq + 3) * ASTR + row] = pb[h].w * sb[h];
        }
    };

    float acc[8][8];
    #pragma unroll
    for (int r = 0; r < 8; ++r)
        #pragma unroll
        for (int c = 0; c < 8; ++c) acc[r][c] = 0.f;

    stage_load(0);
    stage_store(0);
    __syncthreads();

    for (int kt = 0; kt < NKT; ++kt) {
        const int cur = kt & 1;
        if (kt + 1 < NKT) stage_load((kt + 1) * TK);   // prefetch (no wait yet)

        #pragma unroll
        for (int kk = 0; kk < TK; ++kk) {
            const float* ap = &As[cur][kk * ASTR + ty * 8];
            const float* bp = &Bs[cur][kk * ASTR + tx * 8];
            float4 a0 = *(const float4*)ap;
            float4 a1 = *(const float4*)(ap + 4);
            float4 b0 = *(const float4*)bp;
            float4 b1 = *(const float4*)(bp + 4);
            float av[8] = {a0.x,a0.y,a0.z,a0.w,a1.x,a1.y,a1.z,a1.w};
            float bv[8] = {b0.x,b0.y,b0.z,b0.w,b1.x,b1.y,b1.z,b1.w};
            #pragma unroll
            for (int r = 0; r < 8; ++r)
                #pragma unroll
                for (int c = 0; c < 8; ++c)
                    acc[r][c] = fmaf(av[r], bv[c], acc[r][c]);
        }
        if (kt + 1 < NKT) stage_store((kt + 1) & 1);   // write other buffer
        __syncthreads();
    }

    // per-chunk argmax: per-thread over 8 cols, then shfl over 16 tx lanes
    #pragma unroll
    for (int r = 0; r < 8; ++r) {
        float bv = -INFINITY; int bj = 0x7fffffff;
        #pragma unroll
        for (int c = 0; c < 8; ++c) {
            int j = j0 + tx * 8 + c;
            if (j < S && acc[r][c] > bv) { bv = acc[r][c]; bj = j; }
        }
        #pragma unroll
        for (int m = 1; m < 16; m <<= 1) {
            float v2 = __shfl_xor(bv, m, 16);
            int   j2 = __shfl_xor(bj, m, 16);
            if (v2 > bv || (v2 == bv && j2 < bj)) { bv = v2; bj = j2; }
        }
        if (tx == 0) {
            int gi = i0 + ty * 8 + r;
            if (gi < S) {
                size_t o = (size_t)(b * S + gi) * NCHUNK + jc;
                pv[o] = bv;
                pi[o] = bj;
            }
        }
    }
}

// ---------------- 3. image loss: sum((image-target)^2), slotted atomics ----
__global__ __launch_bounds__(256) void image_loss_kernel(
    const float* __restrict__ image, const float* __restrict__ target,
    float* __restrict__ acc)
{
    const size_t n4 = (size_t)B * S_FULL * D / 4;
    float s = 0.f;
    for (size_t i = (size_t)blockIdx.x * 256 + threadIdx.x; i < n4;
         i += (size_t)gridDim.x * 256) {
        float4 a = ((const float4*)image)[i];
        float4 t = ((const float4*)target)[i];
        float dx = a.x - t.x, dy = a.y - t.y, dz = a.z - t.z, dw = a.w - t.w;
        s += dx * dx + dy * dy + dz * dz + dw * dw;
    }
    #pragma unroll
    for (int m = 32; m > 0; m >>= 1) s += __shfl_xor(s, m, 64);
    __shared__ float ls[4];
    int lane = threadIdx.x & 63, w = threadIdx.x >> 6;
    if (lane == 0) ls[w] = s;
    __syncthreads();
    if (threadIdx.x == 0)
        atomicAdd(&acc[blockIdx.x & 63], ls[0] + ls[1] + ls[2] + ls[3]);
}

// ---------------- 4. combine argmax + text loss (wave per row) ----------------
__global__ __launch_bounds__(256) void text_kernel(
    const float* __restrict__ text, const float* __restrict__ target,
    const int* __restrict__ pm,
    const float* __restrict__ pv, const int* __restrict__ pi,
    float* __restrict__ idx_f, float* __restrict__ acc)
{
    int row = blockIdx.x * 4 + (threadIdx.x >> 6);
    if (row >= NROWS) return;
    int lane = threadIdx.x & 63;
    int b = row / S, i = row - b * S;

    float bv = pv[(size_t)row * NCHUNK];
    int   bj = pi[(size_t)row * NCHUNK];
    #pragma unroll
    for (int jc = 1; jc < NCHUNK; ++jc) {
        float v = pv[(size_t)row * NCHUNK + jc];
        int   j = pi[(size_t)row * NCHUNK + jc];
        if (v > bv) { bv = v; bj = j; }   // strict >: earliest chunk wins ties
    }
    if (lane == 0) idx_f[row] = (float)bj;

    if (pm[b * S_FULL + i + 1] != 0) return;

    const float4* pt = (const float4*)(text   + (size_t)(b * S_FULL + i  + 1) * D);
    const float4* pg = (const float4*)(target + (size_t)(b * S_FULL + bj + 1) * D);
    float s = 0.f;
    #pragma unroll
    for (int q = 0; q < 3; ++q) {
        float4 a = pt[lane + 64 * q];
        float4 g = pg[lane + 64 * q];
        float dx = a.x - g.x, dy = a.y - g.y, dz = a.z - g.z, dw = a.w - g.w;
        s += dx * dx + dy * dy + dz * dz + dw * dw;
    }
    #pragma unroll
    for (int m = 32; m > 0; m >>= 1) s += __shfl_xor(s, m, 64);
    if (lane == 0) {
        atomicAdd(&acc[64  + (blockIdx.x & 63)], s);
        atomicAdd(&acc[128 + (blockIdx.x & 63)], 1.0f);
    }
}

// ---------------- 5. finalize ----------------
__global__ void finalize_kernel(const float* __restrict__ acc, float* __restrict__ out)
{
    int lane = threadIdx.x;   // 64 threads
    float si = acc[lane], st = acc[64 + lane], sc = acc[128 + lane];
    #pragma unroll
    for (int m = 32; m > 0; m >>= 1) {
        si += __shfl_xor(si, m, 64);
        st += __shfl_xor(st, m, 64);
        sc += __shfl_xor(sc, m, 64);
    }
    if (lane == 0) {
        float img = si / (float)((size_t)B * S_FULL * D);
        float txt = st / (sc * (float)D);
        out[0] = 0.5f * (txt + img);
        out[1] = txt;
        out[2] = img;
    }
}

extern "C" void kernel_launch(void* const* d_in, const int* in_sizes, int n_in,
                              void* d_out, int out_size, void* d_ws, size_t ws_size,
                              hipStream_t stream) {
    const float* image  = (const float*)d_in[0];
    const float* text   = (const float*)d_in[1];
    const float* target = (const float*)d_in[2];
    const int*   pm     = (const int*)d_in[3];
    float* out = (float*)d_out;

    float* ws    = (float*)d_ws;
    float* inv_t = ws;                         // NROWS
    float* inv_g = ws + NROWS;                 // NROWS
    float* pv    = ws + 2 * NROWS;             // NROWS*4
    int*   pi    = (int*)(ws + 6 * NROWS);     // NROWS*4
    float* acc   = ws + 10 * NROWS;            // 192 slots

    hipMemsetAsync(acc, 0, 192 * sizeof(float), stream);

    norm_kernel<<<(NROWS + 3) / 4, 256, 0, stream>>>(text, target, inv_t, inv_g);
    simargmax_kernel<<<dim3(NCHUNK, NITILE, B), 256, 0, stream>>>(
        text, target, inv_t, inv_g, pv, pi);
    image_loss_kernel<<<2048, 256, 0, stream>>>(image, target, acc);
    text_kernel<<<(NROWS + 3) / 4, 256, 0, stream>>>(
        text, target, pm, pv, pi, out + 3, acc);
    finalize_kernel<<<1, 64, 0, stream>>>(acc, out);
}